// Round 6
// baseline (1974.073 us; speedup 1.0000x reference)
//
#include <hip/hip_runtime.h>
#include <math.h>

// Problem constants (match reference)
#define N_PIX   262144
#define G_NUM   4096
#define K_FREQ  4
#define GSTRIDE 32      // floats per packed gaussian record (128 B)
#define BLOCK   256
#define GSPLIT  8       // gaussian-range split: 512-g work items for balancing
#define NBIN1   64      // spatial bins per axis (64x64 = 4096 bins, ~64 pts/bin)
#define NBINS   (NBIN1*NBIN1)
#define NGRP    (N_PIX / 64)       // 4096 wave-groups of 64 sorted pixels
#define NITEMS  (NGRP * GSPLIT)    // 32768 work items
#define NW      (G_NUM / GSPLIT / 64)  // 8 mask words per item
#define NPOOL   8                  // sharded ticket counters
#define NPP     (NITEMS / NPOOL)   // 4096 items per pool
#define GRID_PERS 2048             // 8 blocks/CU x 256 CU = exactly-capacity
#define GA_CUT  12.0f   // skip pair when min ga over group bbox > CUT (gw < 2^-12)

#if __has_builtin(__builtin_amdgcn_exp2f)
#define EXP2F(x) __builtin_amdgcn_exp2f(x)
#else
#define EXP2F(x) exp2f(x)
#endif

// cos(2*pi*v): v_cos_f32 takes revolutions; v_fract_f32 does range reduction.
__device__ __forceinline__ float cos2pi(float v) {
    return __builtin_amdgcn_cosf(__builtin_amdgcn_fractf(v));
}

// Pack per-gaussian params into a 32-float record:
// [0..3]  px, py, cos(rot), sin(rot)
// [4..7]  isx*S, isy*S, color0, color1      (S = sqrt(0.5*log2(e)))
// [8..10] color2, qxn, qyn   (qxn=-(gx*cr+gy*sr), qyn=gx*sr-gy*cr -> tx,ty via 2 fma)
// [12..15] fx[0..3]  [16..19] cx[0..3]  [20..23] fy[0..3]  [24..27] cy[0..3]
__global__ void prep_kernel(const float* __restrict__ colors,
                            const float* __restrict__ pos,
                            const float* __restrict__ scales,
                            const float* __restrict__ rots,
                            const float* __restrict__ coeffs,
                            const int*   __restrict__ idx,
                            float* __restrict__ gp)
{
    int g = blockIdx.x * blockDim.x + threadIdx.x;
    if (g >= G_NUM) return;
    float sr, cr;
    sincosf(rots[g], &sr, &cr);
    const float SC = 0.84932180028801904f;   // sqrt(0.5 * log2(e))
    float isx = expf(scales[2*g + 0]) * SC;
    float isy = expf(scales[2*g + 1]) * SC;
    float gx = pos[2*g], gy = pos[2*g + 1];
    float* o = gp + (size_t)g * GSTRIDE;
    o[0] = gx;  o[1] = gy;  o[2] = cr;  o[3] = sr;
    o[4] = isx; o[5] = isy;
    o[6] = colors[3*g];  o[7] = colors[3*g + 1];
    o[8] = colors[3*g + 2];
    o[9]  = -(gx*cr + gy*sr);   // qxn
    o[10] =  (gx*sr - gy*cr);   // qyn
    o[11] = 0.f;
    const float FS = 1024.0f / 1024.0f;   // MAXF / NF
#pragma unroll
    for (int k = 0; k < K_FREQ; ++k) {
        o[12 + k] = (float)idx[g*2*K_FREQ + 2*k + 0] * FS;
        o[16 + k] = coeffs[g*2*K_FREQ + 2*k + 0];
        o[20 + k] = (float)idx[g*2*K_FREQ + 2*k + 1] * FS;
        o[24 + k] = coeffs[g*2*K_FREQ + 2*k + 1];
    }
    o[28] = 0.f; o[29] = 0.f; o[30] = 0.f; o[31] = 0.f;
}

__device__ __forceinline__ int bin_of(float2 P) {
    int bx = (int)(P.x * (float)NBIN1); bx = bx > NBIN1-1 ? NBIN1-1 : bx;
    int by = (int)(P.y * (float)NBIN1); by = by > NBIN1-1 ? NBIN1-1 : by;
    return by * NBIN1 + bx;
}

// --- counting sort of pixels into 64x64 spatial bins (3 tiny kernels) ---
__global__ void hist_kernel(const float2* __restrict__ x, int* __restrict__ hist)
{
    int i = blockIdx.x * blockDim.x + threadIdx.x;
    float2 P = x[i];
    atomicAdd(&hist[bin_of(P)], 1);
}

// Single-block Hillis-Steele inclusive scan over 4096 bins -> exclusive starts.
__global__ __launch_bounds__(1024) void scan_kernel(const int* __restrict__ hist,
                                                    int* __restrict__ start)
{
    __shared__ int s[NBINS];
    const int t = threadIdx.x;
    for (int k = t; k < NBINS; k += 1024) s[k] = hist[k];
    __syncthreads();
    for (int off = 1; off < NBINS; off <<= 1) {
        int v[4];
#pragma unroll
        for (int k = 0; k < 4; ++k) {
            int i = t + 1024*k;
            v[k] = (i >= off) ? s[i - off] : 0;
        }
        __syncthreads();
#pragma unroll
        for (int k = 0; k < 4; ++k) s[t + 1024*k] += v[k];
        __syncthreads();
    }
    for (int k = t; k < NBINS; k += 1024) start[k] = s[k] - hist[k];
}

__global__ void scatter_kernel(const float2* __restrict__ x,
                               const int* __restrict__ start,
                               int* __restrict__ cursor,
                               int* __restrict__ sidx,
                               float2* __restrict__ sx)
{
    int i = blockIdx.x * blockDim.x + threadIdx.x;
    float2 P = x[i];
    int b = bin_of(P);
    int pos = start[b] + atomicAdd(&cursor[b], 1);
    sidx[pos] = i;
    sx[pos]   = P;
}

// Per 64-pixel sorted group: conservative survivor bitmask over all 4096
// gaussians. Include gaussian iff min over the group's bbox of ga < GA_CUT.
// bbox-min is a lower bound on any pixel's ga, so exclusion implies the
// per-pixel weight would be < 2^-GA_CUT -> superset of exact survivors.
__global__ __launch_bounds__(BLOCK) void build_kernel(
    const float2* __restrict__ sx,
    const float*  __restrict__ gp,
    unsigned long long* __restrict__ wmask)
{
    const int lane = threadIdx.x & 63;
    const int grp  = blockIdx.x * (BLOCK/64) + (threadIdx.x >> 6);
    float2 P = sx[grp*64 + lane];

    float xmn = P.x, xmx = P.x, ymn = P.y, ymx = P.y;
    for (int m = 32; m; m >>= 1) {
        xmn = fminf(xmn, __shfl_xor(xmn, m));
        xmx = fmaxf(xmx, __shfl_xor(xmx, m));
        ymn = fminf(ymn, __shfl_xor(ymn, m));
        ymx = fmaxf(ymx, __shfl_xor(ymx, m));
    }
    const float cxp = 0.5f*(xmn + xmx), hx = 0.5f*(xmx - xmn);
    const float cyp = 0.5f*(ymn + ymx), hy = 0.5f*(ymx - ymn);

    const float4* q4 = (const float4*)gp;
    for (int w = 0; w < G_NUM/64; ++w) {
        const int gid = w*64 + lane;
        const float4* q = q4 + (size_t)gid * (GSTRIDE/4);
        const float4 A  = q[0];   // px, py, cr, sr
        const float4 Bv = q[1];   // isx', isy', c0, c1
        const float4 C2 = q[2];   // c2, qxn, qyn, -
        float acr = fabsf(A.z), asr = fabsf(A.w);
        float txc = fmaf(cxp, A.z, fmaf(cyp,  A.w, C2.y));
        float tyc = fmaf(cyp, A.z, fmaf(cxp, -A.w, C2.z));
        float rtx = fmaf(hx, acr, hy * asr);
        float rty = fmaf(hx, asr, hy * acr);
        float mtx = fmaxf(0.f, fabsf(txc) - rtx) * Bv.x;
        float mty = fmaxf(0.f, fabsf(tyc) - rty) * Bv.y;
        float gmin = fmaf(mty, mty, mtx * mtx);
        unsigned long long m = __ballot(gmin < GA_CUT);
        if (lane == 0) wmask[(size_t)grp * (G_NUM/64) + w] = m;
    }
}

// Persistent waves + SHARDED dynamic ticket pools (round-5 counter lesson:
// one ticket line at ~30M pops/s was at L2 same-address atomic service rate,
// and the immediate readfirstlane serialized its latency into every item ->
// VALUBusy 75%). NPOOL=8 counters on separate 512B lines, 1024 waves each;
// pool p serves items t*8+p (stride-8 interleave decorrelates item weights
// spatially and across splits -> pool totals within ~1%). The pop is issued
// at the TOP of the body (lane 0), but readfirstlane/wait happens only at
// the BOTTOM, so the atomic round-trip hides under ~50k cy of item work.
// item is wave-uniform -> bitmask walk stays SALU, record loads stay s_load.
__global__ __launch_bounds__(BLOCK) void render_kernel(
    const float2* __restrict__ sx,
    const int*    __restrict__ sidx,
    const float*  __restrict__ gp,
    const unsigned long long* __restrict__ wmask,
    int* __restrict__ ticket,
    float* __restrict__ out)
{
    const int lane = threadIdx.x & 63;
    const int waveid = threadIdx.x >> 6;
    const float4* __restrict__ q4 = (const float4*)gp;

    const int pool = (blockIdx.x * (BLOCK/64) + waveid) & (NPOOL - 1);
    int* __restrict__ tk = ticket + pool * 128;   // 512B-spaced counters

    int t0 = 0;
    if (lane == 0) t0 = atomicAdd(tk, 1);
    int t = __builtin_amdgcn_readfirstlane(t0);

    while (t < NPP) {
        // pop next ticket now; result consumed only at the bottom
        int t1 = 0;
        if (lane == 0) t1 = atomicAdd(tk, 1);

        const int item  = t * NPOOL + pool;
        const int grp   = item & (NGRP - 1);
        const int split = item >> 12;            // NGRP = 4096 = 2^12
        const int gbase = split * (G_NUM / GSPLIT);
        const unsigned long long* mw =
            wmask + (size_t)grp * (G_NUM/64) + split * NW;

        const float2 P  = sx[grp*64 + lane];
        const int   pix = sidx[grp*64 + lane];

        float ar = 0.f, ag = 0.f, ab = 0.f;

        int wi = 0;
        unsigned long long word = mw[0];
        int cur = -1;
        for (;;) {
            if (word) {
                int b = (int)__builtin_ctzll(word);
                word &= word - 1;
                cur = gbase + wi*64 + b;
                break;
            }
            if (++wi >= NW) break;
            word = mw[wi];
        }

        if (cur >= 0) {
            const float4* q = q4 + (size_t)cur * (GSTRIDE/4);
            float4 A  = q[0];
            float4 Bv = q[1];
            float4 C2 = q[2];
            float4 FX = q[3];
            float4 CX = q[4];
            float4 FY = q[5];
            float4 CY = q[6];

            for (;;) {
                // find next set bit (SALU chain, overlaps VALU body below)
                int nxt = -1;
                for (;;) {
                    if (word) {
                        int b = (int)__builtin_ctzll(word);
                        word &= word - 1;
                        nxt = gbase + wi*64 + b;
                        break;
                    }
                    if (++wi >= NW) break;
                    word = mw[wi];
                }
                // prefetch next record (reload current on last iter; harmless)
                const int pidx = (nxt < 0) ? cur : nxt;
                const float4* qn = q4 + (size_t)pidx * (GSTRIDE/4);
                const float4 An  = qn[0];
                const float4 Bn  = qn[1];
                const float4 C2n = qn[2];
                const float4 FXn = qn[3];
                const float4 CXn = qn[4];
                const float4 FYn = qn[5];
                const float4 CYn = qn[6];

                float tx = fmaf(P.x, A.z, fmaf(P.y,  A.w, C2.y));
                float ty = fmaf(P.y, A.z, fmaf(P.x, -A.w, C2.z));
                float bx = tx * Bv.x, by = ty * Bv.y;
                float ga = fmaf(by, by, bx * bx);
                float gw = EXP2F(-ga);

                float wx;
                wx  = CX.x * cos2pi(tx * FX.x);
                wx  = fmaf(CX.y, cos2pi(tx * FX.y), wx);
                wx  = fmaf(CX.z, cos2pi(tx * FX.z), wx);
                wx  = fmaf(CX.w, cos2pi(tx * FX.w), wx);
                float wy;
                wy  = CY.x * cos2pi(ty * FY.x);
                wy  = fmaf(CY.y, cos2pi(ty * FY.y), wy);
                wy  = fmaf(CY.z, cos2pi(ty * FY.z), wy);
                wy  = fmaf(CY.w, cos2pi(ty * FY.w), wy);

                float w = (gw * wx) * wy;
                ar = fmaf(w, Bv.z, ar);
                ag = fmaf(w, Bv.w, ag);
                ab = fmaf(w, C2.x, ab);

                if (nxt < 0) break;
                A = An; Bv = Bn; C2 = C2n; FX = FXn; CX = CXn; FY = FYn; CY = CYn;
                cur = nxt;
            }
        }

        const int o = pix * 3;
        atomicAdd(&out[o + 0], ar);
        atomicAdd(&out[o + 1], ag);
        atomicAdd(&out[o + 2], ab);

        // consume the pop issued at the top; waitcnt lands here, hidden
        t = __builtin_amdgcn_readfirstlane(t1);
    }
}

extern "C" void kernel_launch(void* const* d_in, const int* in_sizes, int n_in,
                              void* d_out, int out_size, void* d_ws, size_t ws_size,
                              hipStream_t stream) {
    const float* x      = (const float*)d_in[0];   // [N,2]
    const float* colors = (const float*)d_in[1];   // [G,3]
    const float* pos    = (const float*)d_in[2];   // [G,2]
    const float* scales = (const float*)d_in[3];   // [G,2]
    const float* rots   = (const float*)d_in[4];   // [G,1]
    const float* coeffs = (const float*)d_in[5];   // [G,K,2]
    const int*   idx    = (const int*)d_in[6];     // [G,K,2]
    float* out = (float*)d_out;

    // Workspace layout (needs ~5.8 MB):
    //   [0, 512K)          gp      gaussian records
    //   [512K, +16K)       hist    bin histogram   (memset each launch)
    //   [528K, +16K)       cursor  scatter cursors (memset each launch)
    //   [544K, +4K)        ticket  8 pool counters, 512B apart (memset)
    //   [548K, +16K)       start   exclusive bin starts
    //   [564K, +1M)        sidx    sorted -> original pixel index
    //   [564K+1M, +2M)     sx      sorted pixel coords (float2)
    //   [564K+3M, +2M)     wmask   per-group survivor bitmasks (4096 x 64 u64)
    char* ws = (char*)d_ws;
    float*  gp     = (float*)(ws);
    int*    hist   = (int*)(ws + 524288);
    int*    cursor = (int*)(ws + 524288 + 16384);
    int*    ticket = (int*)(ws + 524288 + 32768);
    int*    start  = (int*)(ws + 524288 + 36864);
    int*    sidx   = (int*)(ws + 524288 + 53248);
    float2* sx     = (float2*)(ws + 524288 + 53248 + 1048576);
    unsigned long long* wmask =
        (unsigned long long*)(ws + 524288 + 53248 + 1048576 + 2097152);

    prep_kernel<<<(G_NUM + 255) / 256, 256, 0, stream>>>(
        colors, pos, scales, rots, coeffs, idx, gp);

    // zero hist + cursor + tickets (adjacent, 36 KB) and the output
    hipMemsetAsync(hist, 0, 36864, stream);
    hipMemsetAsync(out, 0, (size_t)out_size * sizeof(float), stream);

    hist_kernel<<<N_PIX / 256, 256, 0, stream>>>((const float2*)x, hist);
    scan_kernel<<<1, 1024, 0, stream>>>(hist, start);
    scatter_kernel<<<N_PIX / 256, 256, 0, stream>>>((const float2*)x, start,
                                                    cursor, sidx, sx);
    build_kernel<<<NGRP / (BLOCK/64), BLOCK, 0, stream>>>(sx, gp, wmask);

    render_kernel<<<GRID_PERS, BLOCK, 0, stream>>>(sx, sidx, gp, wmask,
                                                   ticket, out);
}

// Round 7
// 1036.948 us; speedup vs baseline: 1.9037x; 1.9037x over previous
//
#include <hip/hip_runtime.h>
#include <math.h>

// Problem constants (match reference)
#define N_PIX   262144
#define G_NUM   4096
#define K_FREQ  4
#define GSTRIDE 32      // floats per packed gaussian record (128 B)
#define BLOCK   256
#define GSPLIT  8       // gaussian-range split: 512-g work items for balancing
#define NBIN1   64      // spatial bins per axis (64x64 = 4096 bins, ~64 pts/bin)
#define NBINS   (NBIN1*NBIN1)
#define NGRP    (N_PIX / 64)       // 4096 wave-groups of 64 sorted pixels
#define NITEMS  (NGRP * GSPLIT)    // 32768 work items
#define NW      (G_NUM / GSPLIT / 64)  // 8 mask words per item
#define NPOOL   8                  // sharded ticket counters
#define NPP     (NITEMS / NPOOL)   // 4096 items per pool
#define GRID_PERS 2048             // 8 blocks/CU x 256 CU = exactly-capacity
#define GA_CUT  12.0f   // skip pair when min ga over group bbox > CUT (gw < 2^-12)

#if __has_builtin(__builtin_amdgcn_exp2f)
#define EXP2F(x) __builtin_amdgcn_exp2f(x)
#else
#define EXP2F(x) exp2f(x)
#endif

// cos(2*pi*v): v_cos_f32 takes revolutions; v_fract_f32 does range reduction.
__device__ __forceinline__ float cos2pi(float v) {
    return __builtin_amdgcn_cosf(__builtin_amdgcn_fractf(v));
}

// Pack per-gaussian params into a 32-float record:
// [0..3]  px, py, cos(rot), sin(rot)
// [4..7]  isx*S, isy*S, color0, color1      (S = sqrt(0.5*log2(e)))
// [8..10] color2, qxn, qyn   (qxn=-(gx*cr+gy*sr), qyn=gx*sr-gy*cr -> tx,ty via 2 fma)
// [12..15] fx[0..3]  [16..19] cx[0..3]  [20..23] fy[0..3]  [24..27] cy[0..3]
__global__ void prep_kernel(const float* __restrict__ colors,
                            const float* __restrict__ pos,
                            const float* __restrict__ scales,
                            const float* __restrict__ rots,
                            const float* __restrict__ coeffs,
                            const int*   __restrict__ idx,
                            float* __restrict__ gp)
{
    int g = blockIdx.x * blockDim.x + threadIdx.x;
    if (g >= G_NUM) return;
    float sr, cr;
    sincosf(rots[g], &sr, &cr);
    const float SC = 0.84932180028801904f;   // sqrt(0.5 * log2(e))
    float isx = expf(scales[2*g + 0]) * SC;
    float isy = expf(scales[2*g + 1]) * SC;
    float gx = pos[2*g], gy = pos[2*g + 1];
    float* o = gp + (size_t)g * GSTRIDE;
    o[0] = gx;  o[1] = gy;  o[2] = cr;  o[3] = sr;
    o[4] = isx; o[5] = isy;
    o[6] = colors[3*g];  o[7] = colors[3*g + 1];
    o[8] = colors[3*g + 2];
    o[9]  = -(gx*cr + gy*sr);   // qxn
    o[10] =  (gx*sr - gy*cr);   // qyn
    o[11] = 0.f;
    const float FS = 1024.0f / 1024.0f;   // MAXF / NF
#pragma unroll
    for (int k = 0; k < K_FREQ; ++k) {
        o[12 + k] = (float)idx[g*2*K_FREQ + 2*k + 0] * FS;
        o[16 + k] = coeffs[g*2*K_FREQ + 2*k + 0];
        o[20 + k] = (float)idx[g*2*K_FREQ + 2*k + 1] * FS;
        o[24 + k] = coeffs[g*2*K_FREQ + 2*k + 1];
    }
    o[28] = 0.f; o[29] = 0.f; o[30] = 0.f; o[31] = 0.f;
}

__device__ __forceinline__ int bin_of(float2 P) {
    int bx = (int)(P.x * (float)NBIN1); bx = bx > NBIN1-1 ? NBIN1-1 : bx;
    int by = (int)(P.y * (float)NBIN1); by = by > NBIN1-1 ? NBIN1-1 : by;
    return by * NBIN1 + bx;
}

// --- counting sort of pixels into 64x64 spatial bins (3 tiny kernels) ---
__global__ void hist_kernel(const float2* __restrict__ x, int* __restrict__ hist)
{
    int i = blockIdx.x * blockDim.x + threadIdx.x;
    float2 P = x[i];
    atomicAdd(&hist[bin_of(P)], 1);
}

// Single-block Hillis-Steele inclusive scan over 4096 bins -> exclusive starts.
__global__ __launch_bounds__(1024) void scan_kernel(const int* __restrict__ hist,
                                                    int* __restrict__ start)
{
    __shared__ int s[NBINS];
    const int t = threadIdx.x;
    for (int k = t; k < NBINS; k += 1024) s[k] = hist[k];
    __syncthreads();
    for (int off = 1; off < NBINS; off <<= 1) {
        int v[4];
#pragma unroll
        for (int k = 0; k < 4; ++k) {
            int i = t + 1024*k;
            v[k] = (i >= off) ? s[i - off] : 0;
        }
        __syncthreads();
#pragma unroll
        for (int k = 0; k < 4; ++k) s[t + 1024*k] += v[k];
        __syncthreads();
    }
    for (int k = t; k < NBINS; k += 1024) start[k] = s[k] - hist[k];
}

__global__ void scatter_kernel(const float2* __restrict__ x,
                               const int* __restrict__ start,
                               int* __restrict__ cursor,
                               int* __restrict__ sidx,
                               float2* __restrict__ sx)
{
    int i = blockIdx.x * blockDim.x + threadIdx.x;
    float2 P = x[i];
    int b = bin_of(P);
    int pos = start[b] + atomicAdd(&cursor[b], 1);
    sidx[pos] = i;
    sx[pos]   = P;
}

// Per 64-pixel sorted group: conservative survivor bitmask over all 4096
// gaussians. Include gaussian iff min over the group's bbox of ga < GA_CUT.
// bbox-min is a lower bound on any pixel's ga, so exclusion implies the
// per-pixel weight would be < 2^-GA_CUT -> superset of exact survivors.
__global__ __launch_bounds__(BLOCK) void build_kernel(
    const float2* __restrict__ sx,
    const float*  __restrict__ gp,
    unsigned long long* __restrict__ wmask)
{
    const int lane = threadIdx.x & 63;
    const int grp  = blockIdx.x * (BLOCK/64) + (threadIdx.x >> 6);
    float2 P = sx[grp*64 + lane];

    float xmn = P.x, xmx = P.x, ymn = P.y, ymx = P.y;
    for (int m = 32; m; m >>= 1) {
        xmn = fminf(xmn, __shfl_xor(xmn, m));
        xmx = fmaxf(xmx, __shfl_xor(xmx, m));
        ymn = fminf(ymn, __shfl_xor(ymn, m));
        ymx = fmaxf(ymx, __shfl_xor(ymx, m));
    }
    const float cxp = 0.5f*(xmn + xmx), hx = 0.5f*(xmx - xmn);
    const float cyp = 0.5f*(ymn + ymx), hy = 0.5f*(ymx - ymn);

    const float4* q4 = (const float4*)gp;
    for (int w = 0; w < G_NUM/64; ++w) {
        const int gid = w*64 + lane;
        const float4* q = q4 + (size_t)gid * (GSTRIDE/4);
        const float4 A  = q[0];   // px, py, cr, sr
        const float4 Bv = q[1];   // isx', isy', c0, c1
        const float4 C2 = q[2];   // c2, qxn, qyn, -
        float acr = fabsf(A.z), asr = fabsf(A.w);
        float txc = fmaf(cxp, A.z, fmaf(cyp,  A.w, C2.y));
        float tyc = fmaf(cyp, A.z, fmaf(cxp, -A.w, C2.z));
        float rtx = fmaf(hx, acr, hy * asr);
        float rty = fmaf(hx, asr, hy * acr);
        float mtx = fmaxf(0.f, fabsf(txc) - rtx) * Bv.x;
        float mty = fmaxf(0.f, fabsf(tyc) - rty) * Bv.y;
        float gmin = fmaf(mty, mty, mtx * mtx);
        unsigned long long m = __ballot(gmin < GA_CUT);
        if (lane == 0) wmask[(size_t)grp * (G_NUM/64) + w] = m;
    }
}

// Persistent waves + SHARDED dynamic ticket pools. Round-6 counter lesson:
// pool was derived from threadIdx.x>>6, which LLVM's divergence analysis
// marks divergent -> item/mask/record addresses demoted VGPR (SGPR 80->48,
// VGPR 8->28), s_load pipeline destroyed, VALU-busy-equiv +36%. Fix: force
// pool uniform via readfirstlane so EVERYTHING downstream is SGPR again.
// NPOOL=8 counters on separate 512B lines (round-5 lesson: one line at
// ~30M pops/s saturates same-address L2 atomic service); pool p serves
// items t*8+p. Pop issued at TOP of body (lane 0), consumed only at the
// BOTTOM -> atomic round-trip hides under ~50k cy of item work.
__global__ __launch_bounds__(BLOCK) void render_kernel(
    const float2* __restrict__ sx,
    const int*    __restrict__ sidx,
    const float*  __restrict__ gp,
    const unsigned long long* __restrict__ wmask,
    int* __restrict__ ticket,
    float* __restrict__ out)
{
    const int lane = threadIdx.x & 63;
    const float4* __restrict__ q4 = (const float4*)gp;

    // readfirstlane: threadIdx.x>>6 IS wave-uniform but LLVM can't prove it;
    // without this the whole record pipeline demotes to VGPR (round 6).
    const int pool = __builtin_amdgcn_readfirstlane(
        (blockIdx.x * (BLOCK/64) + (threadIdx.x >> 6)) & (NPOOL - 1));
    int* __restrict__ tk = ticket + pool * 128;   // 512B-spaced counters

    int t0 = 0;
    if (lane == 0) t0 = atomicAdd(tk, 1);
    int t = __builtin_amdgcn_readfirstlane(t0);

    while (t < NPP) {
        // pop next ticket now; result consumed only at the bottom
        int t1 = 0;
        if (lane == 0) t1 = atomicAdd(tk, 1);

        const int item  = t * NPOOL + pool;
        const int grp   = item & (NGRP - 1);
        const int split = item >> 12;            // NGRP = 4096 = 2^12
        const int gbase = split * (G_NUM / GSPLIT);
        const unsigned long long* mw =
            wmask + (size_t)grp * (G_NUM/64) + split * NW;

        const float2 P  = sx[grp*64 + lane];
        const int   pix = sidx[grp*64 + lane];

        float ar = 0.f, ag = 0.f, ab = 0.f;

        int wi = 0;
        unsigned long long word = mw[0];
        int cur = -1;
        for (;;) {
            if (word) {
                int b = (int)__builtin_ctzll(word);
                word &= word - 1;
                cur = gbase + wi*64 + b;
                break;
            }
            if (++wi >= NW) break;
            word = mw[wi];
        }

        if (cur >= 0) {
            const float4* q = q4 + (size_t)cur * (GSTRIDE/4);
            float4 A  = q[0];
            float4 Bv = q[1];
            float4 C2 = q[2];
            float4 FX = q[3];
            float4 CX = q[4];
            float4 FY = q[5];
            float4 CY = q[6];

            for (;;) {
                // find next set bit (SALU chain, overlaps VALU body below)
                int nxt = -1;
                for (;;) {
                    if (word) {
                        int b = (int)__builtin_ctzll(word);
                        word &= word - 1;
                        nxt = gbase + wi*64 + b;
                        break;
                    }
                    if (++wi >= NW) break;
                    word = mw[wi];
                }
                // prefetch next record (reload current on last iter; harmless)
                const int pidx = (nxt < 0) ? cur : nxt;
                const float4* qn = q4 + (size_t)pidx * (GSTRIDE/4);
                const float4 An  = qn[0];
                const float4 Bn  = qn[1];
                const float4 C2n = qn[2];
                const float4 FXn = qn[3];
                const float4 CXn = qn[4];
                const float4 FYn = qn[5];
                const float4 CYn = qn[6];

                float tx = fmaf(P.x, A.z, fmaf(P.y,  A.w, C2.y));
                float ty = fmaf(P.y, A.z, fmaf(P.x, -A.w, C2.z));
                float bx = tx * Bv.x, by = ty * Bv.y;
                float ga = fmaf(by, by, bx * bx);
                float gw = EXP2F(-ga);

                float wx;
                wx  = CX.x * cos2pi(tx * FX.x);
                wx  = fmaf(CX.y, cos2pi(tx * FX.y), wx);
                wx  = fmaf(CX.z, cos2pi(tx * FX.z), wx);
                wx  = fmaf(CX.w, cos2pi(tx * FX.w), wx);
                float wy;
                wy  = CY.x * cos2pi(ty * FY.x);
                wy  = fmaf(CY.y, cos2pi(ty * FY.y), wy);
                wy  = fmaf(CY.z, cos2pi(ty * FY.z), wy);
                wy  = fmaf(CY.w, cos2pi(ty * FY.w), wy);

                float w = (gw * wx) * wy;
                ar = fmaf(w, Bv.z, ar);
                ag = fmaf(w, Bv.w, ag);
                ab = fmaf(w, C2.x, ab);

                if (nxt < 0) break;
                A = An; Bv = Bn; C2 = C2n; FX = FXn; CX = CXn; FY = FYn; CY = CYn;
                cur = nxt;
            }
        }

        const int o = pix * 3;
        atomicAdd(&out[o + 0], ar);
        atomicAdd(&out[o + 1], ag);
        atomicAdd(&out[o + 2], ab);

        // consume the pop issued at the top; waitcnt lands here, hidden
        t = __builtin_amdgcn_readfirstlane(t1);
    }
}

extern "C" void kernel_launch(void* const* d_in, const int* in_sizes, int n_in,
                              void* d_out, int out_size, void* d_ws, size_t ws_size,
                              hipStream_t stream) {
    const float* x      = (const float*)d_in[0];   // [N,2]
    const float* colors = (const float*)d_in[1];   // [G,3]
    const float* pos    = (const float*)d_in[2];   // [G,2]
    const float* scales = (const float*)d_in[3];   // [G,2]
    const float* rots   = (const float*)d_in[4];   // [G,1]
    const float* coeffs = (const float*)d_in[5];   // [G,K,2]
    const int*   idx    = (const int*)d_in[6];     // [G,K,2]
    float* out = (float*)d_out;

    // Workspace layout (needs ~5.8 MB):
    //   [0, 512K)          gp      gaussian records
    //   [512K, +16K)       hist    bin histogram   (memset each launch)
    //   [528K, +16K)       cursor  scatter cursors (memset each launch)
    //   [544K, +4K)        ticket  8 pool counters, 512B apart (memset)
    //   [548K, +16K)       start   exclusive bin starts
    //   [564K, +1M)        sidx    sorted -> original pixel index
    //   [564K+1M, +2M)     sx      sorted pixel coords (float2)
    //   [564K+3M, +2M)     wmask   per-group survivor bitmasks (4096 x 64 u64)
    char* ws = (char*)d_ws;
    float*  gp     = (float*)(ws);
    int*    hist   = (int*)(ws + 524288);
    int*    cursor = (int*)(ws + 524288 + 16384);
    int*    ticket = (int*)(ws + 524288 + 32768);
    int*    start  = (int*)(ws + 524288 + 36864);
    int*    sidx   = (int*)(ws + 524288 + 53248);
    float2* sx     = (float2*)(ws + 524288 + 53248 + 1048576);
    unsigned long long* wmask =
        (unsigned long long*)(ws + 524288 + 53248 + 1048576 + 2097152);

    prep_kernel<<<(G_NUM + 255) / 256, 256, 0, stream>>>(
        colors, pos, scales, rots, coeffs, idx, gp);

    // zero hist + cursor + tickets (adjacent, 36 KB) and the output
    hipMemsetAsync(hist, 0, 36864, stream);
    hipMemsetAsync(out, 0, (size_t)out_size * sizeof(float), stream);

    hist_kernel<<<N_PIX / 256, 256, 0, stream>>>((const float2*)x, hist);
    scan_kernel<<<1, 1024, 0, stream>>>(hist, start);
    scatter_kernel<<<N_PIX / 256, 256, 0, stream>>>((const float2*)x, start,
                                                    cursor, sidx, sx);
    build_kernel<<<NGRP / (BLOCK/64), BLOCK, 0, stream>>>(sx, gp, wmask);

    render_kernel<<<GRID_PERS, BLOCK, 0, stream>>>(sx, sidx, gp, wmask,
                                                   ticket, out);
}